// Round 10
// baseline (366.740 us; speedup 1.0000x reference)
//
#include <hip/hip_runtime.h>
#include <stdint.h>

#define N_NODES 20000
#define N_EDGES 320000
#define C 128
#define H 8
#define D 16
#define SLOT 64        // max degree per node per relation (Poisson(16); P(>=64)~1e-18, guarded)
#define NRANGE 5000    // node_p2 ranges of 4 dsts
#define RANGES2 10000  // partition ranges of 2 dsts; 10000*2 == 20000
#define CAP2 80        // records per (rel,range2); mean 32, P(>=80)~1e-11, guarded

// prep_k job partition (block ranges)
#define P_CVT 2500     // 2500*256*4 == N_NODES*C
#define P_ZERO 625     // 40000 cursors * 16 ints = 640000 ints = 160000 int4
#define P_PACK 128
#define P_FUSE 32
// mega_k: 5000 part blocks + 3130 proj blocks, period-13 interleave (8 part + 5 proj)
#define MB_TOTAL 8130

typedef short s16x8 __attribute__((ext_vector_type(8)));
typedef float f32x4 __attribute__((ext_vector_type(4)));

__device__ __forceinline__ unsigned short f2bf(float f) {
    unsigned int b = __float_as_uint(f);
    b += 0x7fffu + ((b >> 16) & 1u);
    return (unsigned short)(b >> 16);
}
__device__ __forceinline__ float bf2f(unsigned int u) {
    return __uint_as_float(u << 16);
}

// ---------------- prep: cvt_h + zero-cursors + pack_wt + fuse_w in ONE dispatch ----------------
__global__ __launch_bounds__(256) void prep_k(const float* __restrict__ h_a, const float* __restrict__ h_b,
                                              unsigned short* __restrict__ oa, unsigned short* __restrict__ ob,
                                              const float* __restrict__ Wq, const float* __restrict__ Wa,
                                              unsigned short* __restrict__ Wqt, unsigned short* __restrict__ Wat,
                                              const float* __restrict__ Wk, const float* __restrict__ Wv,
                                              const float* __restrict__ bk, const float* __restrict__ bv,
                                              const float* __restrict__ att, const float* __restrict__ msg,
                                              unsigned short* __restrict__ Wkt, unsigned short* __restrict__ Wvt,
                                              float* __restrict__ bkt, float* __restrict__ bvt,
                                              int* __restrict__ cur) {
    __shared__ float sa[D * D], sm[D * D];
    int bid = blockIdx.x;
    int tid = threadIdx.x;
    if (bid < P_CVT) {
        int i = (bid * 256 + tid) * 4;
        float4 va = *(const float4*)(h_a + i);
        float4 vb = *(const float4*)(h_b + i);
        ushort4 ua = { f2bf(va.x), f2bf(va.y), f2bf(va.z), f2bf(va.w) };
        ushort4 ub = { f2bf(vb.x), f2bf(vb.y), f2bf(vb.z), f2bf(vb.w) };
        *(ushort4*)(oa + i) = ua;
        *(ushort4*)(ob + i) = ub;
        return;
    }
    bid -= P_CVT;
    if (bid < P_ZERO) {
        int i = bid * 256 + tid;
        if (i < 160000) ((int4*)cur)[i] = make_int4(0, 0, 0, 0);
        return;
    }
    bid -= P_ZERO;
    if (bid < P_PACK) {
        int n = bid;
        int t = tid >> 7, i = tid & 127;
        Wqt[(t * C + n) * C + i] = f2bf(Wq[(t * C + i) * C + n]);
        Wat[(t * C + n) * C + i] = f2bf(Wa[(t * C + i) * C + n]);
        return;
    }
    bid -= P_PACK;
    {
        int r = bid >> 3, h = bid & 7;
        int t = r >> 1;
        if (tid < D * D) {
            sa[tid] = att[(r * H + h) * D * D + tid];
            sm[tid] = msg[(r * H + h) * D * D + tid];
        }
        __syncthreads();
        int i = tid & 127;
        for (int e = (tid >> 7); e < D; e += 2) {
            float sk = 0.f, sv = 0.f;
            for (int d = 0; d < D; ++d) {
                sk += Wk[(t * C + i) * C + h * D + d] * sa[d * D + e];
                sv += Wv[(t * C + i) * C + h * D + d] * sm[d * D + e];
            }
            Wkt[(r * C + h * D + e) * C + i] = f2bf(sk);
            Wvt[(r * C + h * D + e) * C + i] = f2bf(sv);
        }
        if (tid < D) {
            int e = tid;
            float sk = 0.f, sv = 0.f;
            for (int d = 0; d < D; ++d) {
                sk += bk[t * C + h * D + d] * sa[d * D + e];
                sv += bv[t * C + h * D + d] * sm[d * D + e];
            }
            bkt[r * C + h * D + e] = sk;
            bvt[r * C + h * D + e] = sv;
        }
    }
}

// ---------------- mega: edge partition || projections, fine-grained interleave ----------------
// KV output is INTERLEAVED per node row (512B): uint idx 2u = K bf16-pair u,
// uint idx 2u+1 = V bf16-pair u  ->  node_p2 gathers K+V with ONE dwordx2/lane.
__global__ __launch_bounds__(256) void mega_k(const int* __restrict__ s0, const int* __restrict__ s1,
                                              const int* __restrict__ s2, const int* __restrict__ s3,
                                              const int* __restrict__ d0, const int* __restrict__ d1,
                                              const int* __restrict__ d2, const int* __restrict__ d3,
                                              int* __restrict__ cur, unsigned short* __restrict__ part,
                                              const unsigned short* __restrict__ ha,
                                              const unsigned short* __restrict__ hb,
                                              const unsigned short* __restrict__ Wqt,
                                              const unsigned short* __restrict__ Wkt,
                                              const unsigned short* __restrict__ Wvt,
                                              const float* __restrict__ bq,
                                              const float* __restrict__ bkt,
                                              const float* __restrict__ bvt,
                                              unsigned short* __restrict__ Qa,
                                              unsigned short* __restrict__ Qb,
                                              unsigned short* __restrict__ KVall) {
    int bid = blockIdx.x;
    int part_id = -1, proj_id = -1;
    if (bid < 8125) {
        int p = bid / 13, o = bid - p * 13;
        if (o < 8) part_id = p * 8 + o;
        else       proj_id = p * 5 + (o - 8);
    } else {
        proj_id = 3125 + (bid - 8125);
    }

    if (part_id >= 0) {
        // ---- partition path: 2B records, range-of-2 dsts ----
        int r = part_id / 1250;
        int eb = part_id - r * 1250;
        int e = eb * 256 + threadIdx.x;          // 1250*256 == N_EDGES
        const int* dd = (r == 0) ? d0 : (r == 1) ? d1 : (r == 2) ? d2 : d3;
        const int* ss = (r == 0) ? s0 : (r == 1) ? s1 : (r == 2) ? s2 : s3;
        int d = dd[e];
        int range = d >> 1;
        int pos = atomicAdd(&cur[(r * RANGES2 + range) * 16], 1);  // one cursor per 64B line
        if (pos < CAP2)
            part[((size_t)(r * RANGES2 + range)) * CAP2 + pos] =
                (unsigned short)(ss[e] | ((d & 1) << 15));
        return;
    }
    // ---- projection path: 10 jobs x 313 blocks ----
    int j = proj_id / 313;
    int xb = proj_id - j * 313;
    const unsigned short* A;
    const unsigned short* Wt;
    const float* bias;
    unsigned short* Out;
    int kvoff = -1;   // <0: plain layout (Q); else interleave with this ushort offset
    if (j < 2) {
        A = j ? hb : ha; Wt = Wqt + j * C * C; bias = bq + j * C; Out = j ? Qb : Qa;
    } else if (j < 6) {
        int r = j - 2;
        A = (r < 2) ? ha : hb; Wt = Wkt + r * C * C; bias = bkt + r * C;
        Out = KVall + (size_t)r * N_NODES * 256;
        kvoff = 0;    // K pairs at even uints
    } else {
        int r = j - 6;
        A = (r < 2) ? ha : hb; Wt = Wvt + r * C * C; bias = bvt + r * C;
        Out = KVall + (size_t)r * N_NODES * 256;
        kvoff = 2;    // V pairs at odd uints
    }
    int wid = threadIdx.x >> 6, l = threadIdx.x & 63;
    int row_base = xb * 64 + wid * 16;
    int lm = l & 15, q = l >> 4;
    f32x4 acc[8] = {};
    int arow = row_base + lm;
    if (arow >= N_NODES) arow = N_NODES - 1;
    const s16x8* Ap = (const s16x8*)(A + (size_t)arow * C);
#pragma unroll
    for (int kc = 0; kc < 4; ++kc) {
        s16x8 af = Ap[kc * 4 + q];
#pragma unroll
        for (int t = 0; t < 8; ++t) {
            s16x8 bf = *(const s16x8*)(Wt + (t * 16 + lm) * C + kc * 32 + q * 8);
            acc[t] = __builtin_amdgcn_mfma_f32_16x16x32_bf16(af, bf, acc[t], 0, 0, 0);
        }
    }
#pragma unroll
    for (int t = 0; t < 8; ++t) {
        int col = t * 16 + lm;
        float b = bias[col];
        int oidx = (kvoff < 0) ? col : (((col >> 1) << 2) | kvoff | (col & 1));
        int rstride = (kvoff < 0) ? C : 256;
#pragma unroll
        for (int i = 0; i < 4; ++i) {
            int row = row_base + q * 4 + i;
            if (row < N_NODES) Out[(size_t)row * rstride + oidx] = f2bf(acc[t][i] + b);
        }
    }
}

// ---------------- final: out = al*(agg @ Wa + ba) + (1-al)*h ; both types via blockIdx.y ----------------
__global__ __launch_bounds__(256) void final_mm(const unsigned short* __restrict__ AggAll,
                                                const unsigned short* __restrict__ WatAll,
                                                const float* __restrict__ baAll,
                                                const float* __restrict__ skip,
                                                const float* __restrict__ h_a,
                                                const float* __restrict__ h_b,
                                                float* __restrict__ OutAll) {
    int ty = blockIdx.y;
    const unsigned short* Agg = AggAll + (size_t)ty * N_NODES * C;
    const unsigned short* Wat = WatAll + ty * C * C;
    const float* ba = baAll + ty * C;
    const float* h_orig = ty ? h_b : h_a;
    float* Out = OutAll + (size_t)ty * N_NODES * C;
    int wid = threadIdx.x >> 6, l = threadIdx.x & 63;
    int row_base = blockIdx.x * 64 + wid * 16;
    int lm = l & 15, q = l >> 4;
    f32x4 acc[8] = {};
    int arow = row_base + lm;
    if (arow >= N_NODES) arow = N_NODES - 1;
    const s16x8* Ap = (const s16x8*)(Agg + (size_t)arow * C);
#pragma unroll
    for (int kc = 0; kc < 4; ++kc) {
        s16x8 af = Ap[kc * 4 + q];
#pragma unroll
        for (int t = 0; t < 8; ++t) {
            s16x8 bf = *(const s16x8*)(Wat + (t * 16 + lm) * C + kc * 32 + q * 8);
            acc[t] = __builtin_amdgcn_mfma_f32_16x16x32_bf16(af, bf, acc[t], 0, 0, 0);
        }
    }
    float al = 1.f / (1.f + __expf(-skip[ty]));
#pragma unroll
    for (int t = 0; t < 8; ++t) {
        int col = t * 16 + lm;
        float b = ba[col];
#pragma unroll
        for (int i = 0; i < 4; ++i) {
            int row = row_base + q * 4 + i;
            if (row < N_NODES)
                Out[(size_t)row * C + col] = al * (acc[t][i] + b) + (1.f - al) * h_orig[(size_t)row * C + col];
        }
    }
}

// ---------------- P2: LDS-bin + fused scoring/softmax/aggregate ----------------
// One block per (type, 4 dsts); ONE dst per wave; K+V gathered with ONE dwordx2.
__global__ __launch_bounds__(256) void node_p2(const int* __restrict__ cur,
                                               const unsigned short* __restrict__ part,
                                               const uint2* __restrict__ KV2,
                                               const float* __restrict__ pri,
                                               const unsigned int* __restrict__ Qa,
                                               const unsigned int* __restrict__ Qb,
                                               unsigned int* __restrict__ agg) {
    __shared__ unsigned short slot[2][4][SLOT];
    __shared__ int cnt[2][4];
    int g = blockIdx.x;
    int type = (g >= NRANGE) ? 1 : 0;
    int range = g - type * NRANGE;     // covers nodes 4*range .. 4*range+3
    int relA = type ? 1 : 0;           // ab : aa
    int relB = type ? 3 : 2;           // bb : ba
    if (threadIdx.x < 8) ((int*)cnt)[threadIdx.x] = 0;
    __syncthreads();
#pragma unroll
    for (int rr = 0; rr < 2; ++rr) {
        int rel = rr ? relB : relA;
#pragma unroll
        for (int seg = 0; seg < 2; ++seg) {
            int r2 = range * 2 + seg;
            int c = cur[(rel * RANGES2 + r2) * 16];
            if (c > CAP2) c = CAP2;
            const unsigned short* pp = part + ((size_t)(rel * RANGES2 + r2)) * CAP2;
            for (int i = threadIdx.x; i < c; i += 256) {
                unsigned int rec = pp[i];
                int dof = 2 * seg + (rec >> 15);
                int p = atomicAdd(&cnt[rr][dof], 1);
                if (p < SLOT) slot[rr][dof][p] = (unsigned short)(rec & 0x7fffu);
            }
        }
    }
    __syncthreads();

    int wid = threadIdx.x >> 6, l = threadIdx.x & 63;
    int hg = l >> 3;
    int dof = wid;                      // ONE dst per wave
    int n = range * 4 + dof;
    const unsigned int* Q32 = type ? Qb : Qa;
    unsigned int qv = Q32[(size_t)n * 64 + l];
    float q0 = bf2f(qv & 0xffffu), q1 = bf2f(qv >> 16);
    float outx = 0.f, outy = 0.f;

#pragma unroll 1
    for (int rr = 0; rr < 2; ++rr) {
        int rel = rr ? relB : relA;
        const uint2* KVrel = KV2 + (size_t)rel * N_NODES * 64;
        float pv = pri[rel * 8 + hg] * 0.25f;
        int deg = cnt[rr][dof];
        if (deg > SLOT) deg = SLOT;
        float m = -1e30f, sum = 0.f;
        float ax0 = 0.f, ay0 = 0.f, ax1 = 0.f, ay1 = 0.f;
        for (int base = 0; base < deg; base += 16) {
            int cc = deg - base;
            if (cc > 16) cc = 16;
            float s[16];
            unsigned int vv[16];
#pragma unroll
            for (int i = 0; i < 16; ++i) {
                float d = -1e30f;
                unsigned int v = 0;
                if (i < cc) {
                    int sv = slot[rr][dof][base + i];   // LDS broadcast (conflict-free)
                    uint2 kv2 = KVrel[(size_t)sv * 64 + l];  // ONE 8B load: K pair + V pair
                    v = kv2.y;
                    d = q0 * bf2f(kv2.x & 0xffffu) + q1 * bf2f(kv2.x >> 16);
                    d += __shfl_xor(d, 1);
                    d += __shfl_xor(d, 2);
                    d += __shfl_xor(d, 4);              // full dot in all 8 lanes of head
                    d *= pv;
                }
                s[i] = d;
                vv[i] = v;
            }
            float mloc = s[0];
#pragma unroll
            for (int i = 1; i < 16; ++i) mloc = fmaxf(mloc, s[i]);
            float mnew = fmaxf(m, mloc);
            float alpha = __expf(m - mnew);             // first chunk: exp(-inf)=0
            sum *= alpha; ax0 *= alpha; ay0 *= alpha; ax1 *= alpha; ay1 *= alpha;
            m = mnew;
#pragma unroll
            for (int i = 0; i < 16; i += 2) {
                if (i < cc) {
                    float ww = __expf(s[i] - m);
                    sum += ww;
                    ax0 += ww * bf2f(vv[i] & 0xffffu);
                    ay0 += ww * bf2f(vv[i] >> 16);
                }
                if (i + 1 < cc) {
                    float ww = __expf(s[i + 1] - m);
                    sum += ww;
                    ax1 += ww * bf2f(vv[i + 1] & 0xffffu);
                    ay1 += ww * bf2f(vv[i + 1] >> 16);
                }
            }
        }
        if (deg > 0) {
            float rs = 1.f / sum;
            outx += (ax0 + ax1) * rs;
            outy += (ay0 + ay1) * rs;
        }
    }
    // 0.5 = cross_reducer 'mean'; agg stored bf16-packed
    unsigned int packed = (unsigned int)f2bf(0.5f * outx) | ((unsigned int)f2bf(0.5f * outy) << 16);
    agg[((size_t)type * N_NODES + n) * 64 + l] = packed;
}

extern "C" void kernel_launch(void* const* d_in, const int* in_sizes, int n_in,
                              void* d_out, int out_size, void* d_ws, size_t ws_size,
                              hipStream_t stream) {
    const float* h_a  = (const float*)d_in[0];
    const float* h_b  = (const float*)d_in[1];
    const float* Wk   = (const float*)d_in[2];
    const float* bk   = (const float*)d_in[3];
    const float* Wq   = (const float*)d_in[4];
    const float* bq   = (const float*)d_in[5];
    const float* Wv   = (const float*)d_in[6];
    const float* bv   = (const float*)d_in[7];
    const float* Wa   = (const float*)d_in[8];
    const float* ba   = (const float*)d_in[9];
    const float* att  = (const float*)d_in[10];
    const float* msg  = (const float*)d_in[11];
    const float* pri  = (const float*)d_in[12];
    const float* skip = (const float*)d_in[13];
    const int* srcs[4] = {(const int*)d_in[14], (const int*)d_in[16], (const int*)d_in[18], (const int*)d_in[20]};
    const int* dsts[4] = {(const int*)d_in[15], (const int*)d_in[17], (const int*)d_in[19], (const int*)d_in[21]};
    float* out = (float*)d_out;

    char* w = (char*)d_ws;
    auto alloc = [&](size_t bytes) {
        char* p = w;
        w += (bytes + 255) & ~(size_t)255;
        return p;
    };
    unsigned short* ha_bf = (unsigned short*)alloc((size_t)N_NODES * C * 2);
    unsigned short* hb_bf = (unsigned short*)alloc((size_t)N_NODES * C * 2);
    unsigned short* Qa    = (unsigned short*)alloc((size_t)N_NODES * C * 2);
    unsigned short* Qb    = (unsigned short*)alloc((size_t)N_NODES * C * 2);
    unsigned short* KVall = (unsigned short*)alloc((size_t)4 * N_NODES * 256 * 2);  // K/V interleaved
    unsigned short* Wqt   = (unsigned short*)alloc(2 * C * C * 2);
    unsigned short* Wat   = (unsigned short*)alloc(2 * C * C * 2);
    unsigned short* Wkt   = (unsigned short*)alloc(4 * C * C * 2);
    unsigned short* Wvt   = (unsigned short*)alloc(4 * C * C * 2);
    float* bkt            = (float*)alloc(4 * C * 4);
    float* bvt            = (float*)alloc(4 * C * 4);
    int* cur              = (int*)alloc(4 * RANGES2 * 16 * 4);
    unsigned short* part  = (unsigned short*)alloc((size_t)4 * RANGES2 * CAP2 * 2);
    unsigned short* agg   = (unsigned short*)alloc((size_t)2 * N_NODES * C * 2);

    // 1) fused prep: cvt + zero-cursors + pack + fuse
    prep_k<<<P_CVT + P_ZERO + P_PACK + P_FUSE, 256, 0, stream>>>(
        h_a, h_b, ha_bf, hb_bf, Wq, Wa, Wqt, Wat,
        Wk, Wv, bk, bv, att, msg, Wkt, Wvt, bkt, bvt, cur);

    // 2) fused partition || projections (interleaved block map, KV-interleaved output)
    mega_k<<<MB_TOTAL, 256, 0, stream>>>(
        srcs[0], srcs[1], srcs[2], srcs[3],
        dsts[0], dsts[1], dsts[2], dsts[3],
        cur, part,
        ha_bf, hb_bf, Wqt, Wkt, Wvt, bq, bkt, bvt,
        Qa, Qb, KVall);

    // 3) fused scoring + softmax + aggregate; 1 dst per wave
    node_p2<<<2 * NRANGE, 256, 0, stream>>>(cur, part,
                                            (const uint2*)KVall, pri,
                                            (const unsigned int*)Qa, (const unsigned int*)Qb,
                                            (unsigned int*)agg);

    // 4) final skip-gated output, both types
    final_mm<<<dim3(313, 2), 256, 0, stream>>>(agg, Wat, ba, skip, h_a, h_b, out);
}